// Round 1
// baseline (75487.610 us; speedup 1.0000x reference)
//
#include <hip/hip_runtime.h>
#include <hip/hip_cooperative_groups.h>

namespace cg = cooperative_groups;

#define F1 1024
#define F4 4096
#define NB 16      // batch
#define NT 512     // time steps

// =====================================================================
// Kernel 1: Xi = A @ Wi + bias, with gate-column permutation so that the
// recurrence wg's 16 columns are contiguous:
//   original col n = g*1024 + wg*4 + j  ->  stored at wg*16 + g*4 + j
// A rows m in [0,8192): layer0 (a_batch_major=1): x[(b*512 + t)*1024], t=m>>4, b=m&15
//                       layer1: A + m*1024
// =====================================================================
__global__ __launch_bounds__(256) void gemm_xi(
    const float* __restrict__ A, const float* __restrict__ Wi,
    const float* __restrict__ bias, float* __restrict__ Xi, int a_batch_major)
{
    __shared__ __align__(16) float As[16][68];
    __shared__ __align__(16) float Bs[16][68];
    const int tid = threadIdx.x;
    const int n0 = blockIdx.x * 64;
    const int m0 = blockIdx.y * 64;

    const int lrow = tid >> 2, lkq = tid & 3;   // A load: row, k-quarter
    const int bkr = tid >> 4, bnq = tid & 15;   // B load: k-row, n-quarter
    const int tm = tid & 15, tn = tid >> 4;     // compute: 4x4 micro tile

    const int m_l = m0 + lrow;
    const float* arow;
    if (a_batch_major) {
        int t = m_l >> 4, b = m_l & 15;
        arow = A + (size_t)(b * NT + t) * F1;
    } else {
        arow = A + (size_t)m_l * F1;
    }

    float acc[4][4];
#pragma unroll
    for (int i = 0; i < 4; i++)
#pragma unroll
        for (int j = 0; j < 4; j++) acc[i][j] = 0.f;

    for (int kc = 0; kc < F1; kc += 16) {
        float4 a4 = *(const float4*)(arow + kc + lkq * 4);
        float4 b4 = *(const float4*)(Wi + (size_t)(kc + bkr) * F4 + n0 + bnq * 4);
        __syncthreads();
        As[lkq * 4 + 0][lrow] = a4.x;
        As[lkq * 4 + 1][lrow] = a4.y;
        As[lkq * 4 + 2][lrow] = a4.z;
        As[lkq * 4 + 3][lrow] = a4.w;
        *(float4*)&Bs[bkr][bnq * 4] = b4;
        __syncthreads();
#pragma unroll
        for (int k = 0; k < 16; k++) {
            const float4 av = *(const float4*)&As[k][tm * 4];
            const float4 bv = *(const float4*)&Bs[k][tn * 4];
            float a_[4] = {av.x, av.y, av.z, av.w};
            float b_[4] = {bv.x, bv.y, bv.z, bv.w};
#pragma unroll
            for (int i = 0; i < 4; i++)
#pragma unroll
                for (int j = 0; j < 4; j++)
                    acc[i][j] = fmaf(a_[i], b_[j], acc[i][j]);
        }
    }

    // epilogue: add bias, store permuted
    const int n = n0 + tn * 4;              // original col base (multiple of 4)
    const int g = n >> 10;                  // gate
    const int wgi = (n & 1023) >> 2;        // owning recurrence wg
    const int np = wgi * 16 + g * 4;        // permuted col base
    const float4 bi = *(const float4*)(bias + n);
#pragma unroll
    for (int i = 0; i < 4; i++) {
        int m = m0 + tm * 4 + i;
        float4 o;
        o.x = acc[i][0] + bi.x;
        o.y = acc[i][1] + bi.y;
        o.z = acc[i][2] + bi.z;
        o.w = acc[i][3] + bi.w;
        *(float4*)(Xi + (size_t)m * F4 + np) = o;
    }
}

// =====================================================================
// Kernel 2: persistent cooperative LSTM recurrence for one layer.
// Grid: 256 wgs x 512 threads. wg owns h-cols [wg*4, wg*4+4) i.e. gate cols
// g*1024 + wg*4 + j for g in 0..3, j in 0..3.
// Thread decomposition: tid = ks*16 + rb*4 + g  (ks: 32-wide K slice,
// rb: 4-row block, g: gate / 4-col block). Wh slice lives in registers
// (wh[32][4] per thread). h staged per step into bank-swizzled LDS.
// =====================================================================
__global__ __launch_bounds__(512, 2) void lstm_recur(
    const float* __restrict__ Wh,   // [1024][4096] layer slice
    const float* __restrict__ Xi,   // [512*16][4096] permuted cols
    const float* __restrict__ c0,   // [16][1024] layer slice
    const float* __restrict__ h0,   // [16][1024] layer slice
    float* __restrict__ Hbuf,       // [16][1024] broadcast buffer (ws)
    float* __restrict__ hseq,       // hseq[t*st_t + b*st_b + col]
    long long st_t, long long st_b,
    float* __restrict__ cfin, float* __restrict__ hfin)
{
    cg::grid_group grid = cg::this_grid();
    const int tid = threadIdx.x;
    const int wg = blockIdx.x;       // 0..255

    const int ks = tid >> 4;         // 0..31
    const int rb = (tid >> 2) & 3;   // 0..3
    const int g = tid & 3;           // 0..3

    __shared__ __align__(16) float4 hbuf4[16 * 257];  // [16 rows][256 float4 + pad], swizzled
    __shared__ __align__(16) float4 red4[32 * 65];    // [32 ks][16 r * 4 g  + pad]
    __shared__ float gbuf[16 * 20];                   // gates [16 rows][16 cols + pad]

    // ---- Wh -> registers: wh[kk][j] = Wh[ks*32+kk][g*1024 + wg*4 + j]
    float wh[32][4];
    {
        const float* wp = Wh + (size_t)(ks * 32) * F4 + g * F1 + wg * 4;
#pragma unroll
        for (int kk = 0; kk < 32; kk++) {
            float4 w4 = *(const float4*)(wp + (size_t)kk * F4);
            wh[kk][0] = w4.x; wh[kk][1] = w4.y; wh[kk][2] = w4.z; wh[kk][3] = w4.w;
        }
    }

    // ---- c-state in registers of the 64 activation threads
    const int ab = tid >> 2, aj = tid & 3;  // act mapping (valid for tid<64)
    float creg = 0.f;
    if (tid < 64) creg = c0[ab * F1 + wg * 4 + aj];

    for (int t = 0; t < NT; ++t) {
        // ---- stage h (16x1024 fp32) into swizzled LDS
        const float* hsrc = (t == 0) ? h0 : Hbuf;
#pragma unroll
        for (int c = 0; c < 8; ++c) {
            int f4 = c * 512 + tid;          // 0..4095
            int r = f4 >> 8;                 // row 0..15
            int k4 = f4 & 255;               // float4 index within row
            float4 v = *(const float4*)(hsrc + r * F1 + k4 * 4);
            int slot = k4 ^ ((k4 >> 3) & 7);
            hbuf4[r * 257 + slot] = v;
        }
        // ---- Xi prefetch into register (consumed in reduce phase)
        float xiv = 0.f;
        if (tid < 256) {
            int r = tid >> 4, c = tid & 15;
            xiv = Xi[(size_t)(t * NB + r) * F4 + wg * 16 + c];
        }
        __syncthreads();

        // ---- GEMM phase: acc[i][j] = sum_{k in slice} h[rb*4+i][k] * Wh[k][col(g,j)]
        float acc[4][4];
#pragma unroll
        for (int i = 0; i < 4; i++) {
            acc[i][0] = 0.f; acc[i][1] = 0.f; acc[i][2] = 0.f; acc[i][3] = 0.f;
        }
#pragma unroll
        for (int s = 0; s < 8; ++s) {
            const int k4 = (ks << 3) + s;
            const int slot = k4 ^ ((k4 >> 3) & 7);
            float4 hv[4];
#pragma unroll
            for (int i = 0; i < 4; i++) hv[i] = hbuf4[(rb * 4 + i) * 257 + slot];
#pragma unroll
            for (int i = 0; i < 4; i++) {
#pragma unroll
                for (int j = 0; j < 4; j++) {
                    acc[i][j] = fmaf(hv[i].x, wh[s * 4 + 0][j], acc[i][j]);
                    acc[i][j] = fmaf(hv[i].y, wh[s * 4 + 1][j], acc[i][j]);
                    acc[i][j] = fmaf(hv[i].z, wh[s * 4 + 2][j], acc[i][j]);
                    acc[i][j] = fmaf(hv[i].w, wh[s * 4 + 3][j], acc[i][j]);
                }
            }
        }
        // ---- write partials: red float idx = ks*260 + r*16 + (g*4+j)
#pragma unroll
        for (int i = 0; i < 4; i++)
            red4[ks * 65 + (rb * 4 + i) * 4 + g] =
                make_float4(acc[i][0], acc[i][1], acc[i][2], acc[i][3]);
        __syncthreads();

        // ---- final reduce over 32 K-slices + Xi -> gates
        if (tid < 256) {
            const float* rf = (const float*)red4;
            float s = xiv;
#pragma unroll
            for (int kss = 0; kss < 32; ++kss) s += rf[kss * 260 + tid];
            int r = tid >> 4, c = tid & 15;
            gbuf[r * 20 + c] = s;
        }
        __syncthreads();

        // ---- activations (64 threads: 16 rows x 4 cols)
        if (tid < 64) {
            float gi = gbuf[ab * 20 + 0 + aj];
            float gf = gbuf[ab * 20 + 4 + aj];
            float gg = gbuf[ab * 20 + 8 + aj];
            float go = gbuf[ab * 20 + 12 + aj];
            float si = 1.f / (1.f + __expf(-gi));
            float sf = 1.f / (1.f + __expf(-gf));
            float so = 1.f / (1.f + __expf(-go));
            float tg = 1.f - 2.f / (__expf(2.f * gg) + 1.f);   // tanh, overflow-safe
            float cn = sf * creg + si * tg;
            float tc = 1.f - 2.f / (__expf(2.f * cn) + 1.f);
            float hn = so * tc;
            creg = cn;
            int col = wg * 4 + aj;
            Hbuf[ab * F1 + col] = hn;
            hseq[(size_t)t * st_t + (size_t)ab * st_b + col] = hn;
            if (t == NT - 1) {
                cfin[ab * F1 + col] = cn;
                hfin[ab * F1 + col] = hn;
            }
        }
        __threadfence();
        grid.sync();
    }
}

// =====================================================================
// Launch
// =====================================================================
extern "C" void kernel_launch(void* const* d_in, const int* in_sizes, int n_in,
                              void* d_out, int out_size, void* d_ws, size_t ws_size,
                              hipStream_t stream) {
    const float* x = (const float*)d_in[0];     // [16][512][1024]
    const float* Wi = (const float*)d_in[1];    // [2][1024][4096]
    const float* Wh = (const float*)d_in[2];    // [2][1024][4096]
    const float* bias = (const float*)d_in[3];  // [2][4096]
    const float* c0 = (const float*)d_in[4];    // [2][16][1024]
    const float* h0 = (const float*)d_in[5];    // [2][16][1024]
    float* out = (float*)d_out;                 // out[16][512][1024] ++ cfin[2][16][1024] ++ hfin[2][16][1024]

    float* Xi = (float*)d_ws;                            // 8192*4096 fp32 = 128MB
    float* Hbuf = Xi + (size_t)8192 * 4096;              // 16*1024

    float* hseq0 = out;                                  // park layer-0 h_seq in out region (32MB)
    float* cfin = out + (size_t)NB * NT * F1;            // + 8388608
    float* hfin = cfin + 2 * NB * F1;                    // + 32768

    const size_t lw = (size_t)F1 * F4;  // layer weight stride
    dim3 ggrid(64, 128), gblk(256);

    // ---------------- layer 0 ----------------
    gemm_xi<<<ggrid, gblk, 0, stream>>>(x, Wi, bias, Xi, 1);
    {
        const float* a0 = Wh;
        const float* a1 = Xi;
        const float* a2 = c0;
        const float* a3 = h0;
        float* a4 = Hbuf;
        float* a5 = hseq0;                 // [t][b][f]
        long long a6 = (long long)NB * F1; // st_t
        long long a7 = F1;                 // st_b
        float* a8 = cfin;                  // layer 0 slice
        float* a9 = hfin;
        void* args[] = {&a0, &a1, &a2, &a3, &a4, &a5, &a6, &a7, &a8, &a9};
        hipLaunchCooperativeKernel((void*)lstm_recur, dim3(256), dim3(512), args, 0, stream);
    }
    // ---------------- layer 1 ----------------
    gemm_xi<<<ggrid, gblk, 0, stream>>>(hseq0, Wi + lw, bias + F4, Xi, 0);
    {
        const float* a0 = Wh + lw;
        const float* a1 = Xi;
        const float* a2 = c0 + NB * F1;
        const float* a3 = h0 + NB * F1;
        float* a4 = Hbuf;
        float* a5 = out;                    // out[b][t][f]
        long long a6 = F1;                  // st_t
        long long a7 = (long long)NT * F1;  // st_b
        float* a8 = cfin + NB * F1;         // layer 1 slice
        float* a9 = hfin + NB * F1;
        void* args[] = {&a0, &a1, &a2, &a3, &a4, &a5, &a6, &a7, &a8, &a9};
        hipLaunchCooperativeKernel((void*)lstm_recur, dim3(256), dim3(512), args, 0, stream);
    }
}

// Round 2
// 10127.354 us; speedup vs baseline: 7.4538x; 7.4538x over previous
//
#include <hip/hip_runtime.h>

#define F1 1024
#define F4 4096
#define NB 16      // batch
#define NT 512     // time steps
#define NWG 256    // recurrence workgroups

typedef float f32x4 __attribute__((ext_vector_type(4)));

// =====================================================================
// Kernel 1: Xi = A @ Wi + bias, with gate-column permutation so that the
// recurrence wg's 16 columns are contiguous:
//   original col n = g*1024 + wg*4 + j  ->  stored at wg*16 + g*4 + j
// A rows m in [0,8192): layer0 (a_batch_major=1): x[(b*512 + t)*1024], t=m>>4, b=m&15
//                       layer1: A + m*1024
// =====================================================================
__global__ __launch_bounds__(256) void gemm_xi(
    const float* __restrict__ A, const float* __restrict__ Wi,
    const float* __restrict__ bias, float* __restrict__ Xi, int a_batch_major)
{
    __shared__ __align__(16) float As[16][68];
    __shared__ __align__(16) float Bs[16][68];
    const int tid = threadIdx.x;
    const int n0 = blockIdx.x * 64;
    const int m0 = blockIdx.y * 64;

    const int lrow = tid >> 2, lkq = tid & 3;   // A load: row, k-quarter
    const int bkr = tid >> 4, bnq = tid & 15;   // B load: k-row, n-quarter
    const int tm = tid & 15, tn = tid >> 4;     // compute: 4x4 micro tile

    const int m_l = m0 + lrow;
    const float* arow;
    if (a_batch_major) {
        int t = m_l >> 4, b = m_l & 15;
        arow = A + (size_t)(b * NT + t) * F1;
    } else {
        arow = A + (size_t)m_l * F1;
    }

    float acc[4][4];
#pragma unroll
    for (int i = 0; i < 4; i++)
#pragma unroll
        for (int j = 0; j < 4; j++) acc[i][j] = 0.f;

    for (int kc = 0; kc < F1; kc += 16) {
        float4 a4 = *(const float4*)(arow + kc + lkq * 4);
        float4 b4 = *(const float4*)(Wi + (size_t)(kc + bkr) * F4 + n0 + bnq * 4);
        __syncthreads();
        As[lkq * 4 + 0][lrow] = a4.x;
        As[lkq * 4 + 1][lrow] = a4.y;
        As[lkq * 4 + 2][lrow] = a4.z;
        As[lkq * 4 + 3][lrow] = a4.w;
        *(float4*)&Bs[bkr][bnq * 4] = b4;
        __syncthreads();
#pragma unroll
        for (int k = 0; k < 16; k++) {
            const float4 av = *(const float4*)&As[k][tm * 4];
            const float4 bv = *(const float4*)&Bs[k][tn * 4];
            float a_[4] = {av.x, av.y, av.z, av.w};
            float b_[4] = {bv.x, bv.y, bv.z, bv.w};
#pragma unroll
            for (int i = 0; i < 4; i++)
#pragma unroll
                for (int j = 0; j < 4; j++)
                    acc[i][j] = fmaf(a_[i], b_[j], acc[i][j]);
        }
    }

    // epilogue: add bias, store permuted
    const int n = n0 + tn * 4;              // original col base (multiple of 4)
    const int g = n >> 10;                  // gate
    const int wgi = (n & 1023) >> 2;        // owning recurrence wg
    const int np = wgi * 16 + g * 4;        // permuted col base
    const float4 bi = *(const float4*)(bias + n);
#pragma unroll
    for (int i = 0; i < 4; i++) {
        int m = m0 + tm * 4 + i;
        float4 o;
        o.x = acc[i][0] + bi.x;
        o.y = acc[i][1] + bi.y;
        o.z = acc[i][2] + bi.z;
        o.w = acc[i][3] + bi.w;
        *(float4*)(Xi + (size_t)m * F4 + np) = o;
    }
}

// =====================================================================
// Kernel 2: persistent LSTM recurrence, one layer.
// Grid 256 wgs x 512 threads (cooperative launch for co-residency only;
// NO cg::sync — custom relaxed-atomic barrier + sc1-coherent h exchange,
// so no per-step L2 writeback/invalidate).
// h double-buffered by step parity: step t reads Hb[t&1] (h_t), writes
// Hb[(t+1)&1] (h_{t+1}).
// =====================================================================
__global__ __launch_bounds__(512, 1) void lstm_recur(
    const float* __restrict__ Wh,   // [1024][4096] layer slice
    const float* __restrict__ Xi,   // [512*16][4096] permuted cols
    const float* __restrict__ c0,   // [16][1024] layer slice
    const float* __restrict__ h0,   // [16][1024] layer slice
    float* __restrict__ Hb,         // [2][16][1024] double-buffered broadcast (ws)
    unsigned* __restrict__ cnt,     // barrier counter (ws, memset to 0)
    unsigned tbase,                 // barrier target base for this layer
    float* __restrict__ hseq,       // hseq[t*st_t + b*st_b + col]
    long long st_t, long long st_b,
    float* __restrict__ cfin, float* __restrict__ hfin)
{
    const int tid = threadIdx.x;
    const int wg = blockIdx.x;       // 0..255

    const int ks = tid >> 4;         // 0..31 (K slice)
    const int rb = (tid >> 2) & 3;   // 0..3  (row block)
    const int g = tid & 3;           // 0..3  (gate)

    __shared__ __align__(16) f32x4 hbuf4[16 * 257];  // h swizzled [16 rows][256+pad]
    __shared__ __align__(16) f32x4 red4[32 * 65];    // partials [32 ks][16r*4g + pad]
    __shared__ float gbuf[16 * 20];                  // gates [16 rows][16 + pad]

    // ---- Wh -> registers: wh[kk][j] = Wh[ks*32+kk][g*1024 + wg*4 + j]
    float wh[32][4];
    {
        const float* wp = Wh + (size_t)(ks * 32) * F4 + g * F1 + wg * 4;
#pragma unroll
        for (int kk = 0; kk < 32; kk++) {
            float4 w4 = *(const float4*)(wp + (size_t)kk * F4);
            wh[kk][0] = w4.x; wh[kk][1] = w4.y; wh[kk][2] = w4.z; wh[kk][3] = w4.w;
        }
    }

    // ---- c-state in registers of the 64 activation threads (= wave 0)
    const int ab = tid >> 2, aj = tid & 3;
    float creg = 0.f;
    if (tid < 64) creg = c0[ab * F1 + wg * 4 + aj];

    for (int t = 0; t < NT; ++t) {
        // ---- gather h (16x1024 fp32). t==0: cached read of h0.
        // t>0: sc1 loads (coherent point) of Hb[t&1] — bypass stale L2s.
        f32x4 vv[8];
        if (t == 0) {
#pragma unroll
            for (int c = 0; c < 8; ++c) {
                int f4 = c * 512 + tid;
                vv[c] = *((const f32x4*)h0 + f4);
            }
        } else {
            const f32x4* hsrc = (const f32x4*)(Hb + (size_t)(t & 1) * (NB * F1));
#pragma unroll
            for (int c = 0; c < 8; ++c) {
                int f4 = c * 512 + tid;
                asm volatile("global_load_dwordx4 %0, %1, off sc1"
                             : "=v"(vv[c]) : "v"(hsrc + f4));
            }
            asm volatile("s_waitcnt vmcnt(0)" ::: "memory");
        }
#pragma unroll
        for (int c = 0; c < 8; ++c) {
            int f4 = c * 512 + tid;
            int r = f4 >> 8, k4 = f4 & 255;
            hbuf4[r * 257 + (k4 ^ ((k4 >> 3) & 7))] = vv[c];
        }
        // ---- Xi prefetch (cached, L2-friendly)
        float xiv = 0.f;
        if (tid < 256) {
            int r = tid >> 4, c = tid & 15;
            xiv = Xi[(size_t)(t * NB + r) * F4 + wg * 16 + c];
        }
        __syncthreads();

        // ---- GEMM: acc[i][j] = sum_{k in slice} h[rb*4+i][k] * wh[k][j]
        float acc[4][4];
#pragma unroll
        for (int i = 0; i < 4; i++) {
            acc[i][0] = 0.f; acc[i][1] = 0.f; acc[i][2] = 0.f; acc[i][3] = 0.f;
        }
#pragma unroll
        for (int s = 0; s < 8; ++s) {
            const int k4 = (ks << 3) + s;
            const int slot = k4 ^ ((k4 >> 3) & 7);
            f32x4 hv[4];
#pragma unroll
            for (int i = 0; i < 4; i++) hv[i] = hbuf4[(rb * 4 + i) * 257 + slot];
#pragma unroll
            for (int i = 0; i < 4; i++) {
#pragma unroll
                for (int j = 0; j < 4; j++) {
                    acc[i][j] = fmaf(hv[i].x, wh[s * 4 + 0][j], acc[i][j]);
                    acc[i][j] = fmaf(hv[i].y, wh[s * 4 + 1][j], acc[i][j]);
                    acc[i][j] = fmaf(hv[i].z, wh[s * 4 + 2][j], acc[i][j]);
                    acc[i][j] = fmaf(hv[i].w, wh[s * 4 + 3][j], acc[i][j]);
                }
            }
        }
#pragma unroll
        for (int i = 0; i < 4; i++)
            red4[ks * 65 + (rb * 4 + i) * 4 + g] =
                (f32x4){acc[i][0], acc[i][1], acc[i][2], acc[i][3]};
        __syncthreads();

        // ---- reduce over 32 K-slices + Xi -> gates
        if (tid < 256) {
            const float* rf = (const float*)red4;
            float s = xiv;
#pragma unroll
            for (int kss = 0; kss < 32; ++kss) s += rf[kss * 260 + tid];
            int r = tid >> 4, c = tid & 15;
            gbuf[r * 20 + c] = s;
        }
        __syncthreads();

        // ---- activations (wave 0: 16 rows x 4 cols), h broadcast via sc1
        if (tid < 64) {
            float gi = gbuf[ab * 20 + 0 + aj];
            float gf = gbuf[ab * 20 + 4 + aj];
            float gg = gbuf[ab * 20 + 8 + aj];
            float go = gbuf[ab * 20 + 12 + aj];
            float si = 1.f / (1.f + __expf(-gi));
            float sf = 1.f / (1.f + __expf(-gf));
            float so = 1.f / (1.f + __expf(-go));
            float tg = 1.f - 2.f / (__expf(2.f * gg) + 1.f);
            float cn = sf * creg + si * tg;
            float tc = 1.f - 2.f / (__expf(2.f * cn) + 1.f);
            float hn = so * tc;
            creg = cn;
            int col = wg * 4 + aj;
            float* hp = Hb + (size_t)((t + 1) & 1) * (NB * F1) + ab * F1 + col;
            __hip_atomic_store(hp, hn, __ATOMIC_RELAXED, __HIP_MEMORY_SCOPE_AGENT);
            hseq[(size_t)t * st_t + (size_t)ab * st_b + col] = hn;
            if (t == NT - 1) {
                cfin[ab * F1 + col] = cn;
                hfin[ab * F1 + col] = hn;
            }
            // wave 0 (the only h-writer): drain stores to coherent point
            asm volatile("s_waitcnt vmcnt(0)" ::: "memory");
        }
        // ---- flat relaxed barrier (no cache maintenance)
        if (tid == 0) {
            unsigned target = tbase + (unsigned)(t + 1) * NWG;
            unsigned prev = __hip_atomic_fetch_add(cnt, 1u, __ATOMIC_RELAXED,
                                                   __HIP_MEMORY_SCOPE_AGENT);
            if (prev + 1u < target) {
                while (__hip_atomic_load(cnt, __ATOMIC_RELAXED,
                                         __HIP_MEMORY_SCOPE_AGENT) < target) {}
            }
        }
        __syncthreads();
    }
}

// =====================================================================
// Launch
// =====================================================================
extern "C" void kernel_launch(void* const* d_in, const int* in_sizes, int n_in,
                              void* d_out, int out_size, void* d_ws, size_t ws_size,
                              hipStream_t stream) {
    const float* x = (const float*)d_in[0];     // [16][512][1024]
    const float* Wi = (const float*)d_in[1];    // [2][1024][4096]
    const float* Wh = (const float*)d_in[2];    // [2][1024][4096]
    const float* bias = (const float*)d_in[3];  // [2][4096]
    const float* c0 = (const float*)d_in[4];    // [2][16][1024]
    const float* h0 = (const float*)d_in[5];    // [2][16][1024]
    float* out = (float*)d_out;                 // out[16][512][1024] ++ cfin[2][16][1024] ++ hfin[2][16][1024]

    float* Xi = (float*)d_ws;                            // 8192*4096 fp32 = 128MB
    float* Hb = Xi + (size_t)8192 * 4096;                // [2][16][1024]
    unsigned* cnt = (unsigned*)(Hb + 2 * NB * F1);       // barrier counter

    float* hseq0 = out;                                  // park layer-0 h_seq in out region
    float* cfin = out + (size_t)NB * NT * F1;
    float* hfin = cfin + 2 * NB * F1;

    const size_t lw = (size_t)F1 * F4;
    dim3 ggrid(64, 128), gblk(256);

    hipMemsetAsync(cnt, 0, 256, stream);  // zero barrier counter (in-graph, every call)

    // ---------------- layer 0 ----------------
    gemm_xi<<<ggrid, gblk, 0, stream>>>(x, Wi, bias, Xi, 1);
    {
        const float* a0 = Wh;
        const float* a1 = Xi;
        const float* a2 = c0;
        const float* a3 = h0;
        float* a4 = Hb;
        unsigned* a5 = cnt;
        unsigned a6 = 0;                   // tbase
        float* a7 = hseq0;                 // [t][b][f]
        long long a8 = (long long)NB * F1; // st_t
        long long a9 = F1;                 // st_b
        float* a10 = cfin;
        float* a11 = hfin;
        void* args[] = {&a0, &a1, &a2, &a3, &a4, &a5, &a6, &a7, &a8, &a9, &a10, &a11};
        hipLaunchCooperativeKernel((void*)lstm_recur, dim3(NWG), dim3(512), args, 0, stream);
    }
    // ---------------- layer 1 ----------------
    gemm_xi<<<ggrid, gblk, 0, stream>>>(hseq0, Wi + lw, bias + F4, Xi, 0);
    {
        const float* a0 = Wh + lw;
        const float* a1 = Xi;
        const float* a2 = c0 + NB * F1;
        const float* a3 = h0 + NB * F1;
        float* a4 = Hb;
        unsigned* a5 = cnt;
        unsigned a6 = (unsigned)NT * NWG;  // tbase (counter continues)
        float* a7 = out;                   // out[b][t][f]
        long long a8 = F1;                 // st_t
        long long a9 = (long long)NT * F1; // st_b
        float* a10 = cfin + NB * F1;
        float* a11 = hfin + NB * F1;
        void* args[] = {&a0, &a1, &a2, &a3, &a4, &a5, &a6, &a7, &a8, &a9, &a10, &a11};
        hipLaunchCooperativeKernel((void*)lstm_recur, dim3(NWG), dim3(512), args, 0, stream);
    }
}